// Round 9
// baseline (56.574 us; speedup 1.0000x reference)
//
#include <hip/hip_runtime.h>

#define SEQ 512
#define EMB 768
#define K3E 2304
#define DHD 48

// ============================================================================
// K0: pun[128,768] = masked gather-mean of lhs rows; also zeroes out[128,100]
// (atomic accumulation target for K2). 96 x 256 thr.
// ============================================================================
__global__ __launch_bounds__(256) void k0_pun(
    const float* __restrict__ lhs, const int* __restrict__ loc,
    float* __restrict__ pun, float* __restrict__ outz)
{
  int id = blockIdx.x * 256 + threadIdx.x;   // 24576 = 128 * 192
  if (id < 3200)                             // 12800 floats of out
    *(float4*)&outz[id * 4] = make_float4(0.f, 0.f, 0.f, 0.f);
  int row = id / 192;
  int ch  = id - row * 192;
  int cnt = 0;
  float4 s = make_float4(0.f, 0.f, 0.f, 0.f);
#pragma unroll
  for (int j = 0; j < 5; j++) {
    int v = loc[row * 5 + j];
    if (v >= 0) {
      float4 wv = *(const float4*)&lhs[((size_t)row * SEQ + v) * EMB + ch * 4];
      s.x += wv.x; s.y += wv.y; s.z += wv.z; s.w += wv.w;
      cnt++;
    }
  }
  float inv = 1.0f / (float)cnt;
  *(float4*)&pun[(size_t)row * EMB + ch * 4] =
      make_float4(s.x * inv, s.y * inv, s.z * inv, s.w * inv);
}

// ============================================================================
// K1 (R5-verbatim config, best measured): blocks 0..575 proj GEMM (16x32),
// blocks 576..743 W_comb (16x32), block 744 bias_comb.
// 512 thr = 8 waves, wave-private K=96 (6 steps BK=16), dbuf LDS, zero
// K-loop barriers, 2x4 microtile. LDS 56 KB -> 2 blocks/CU.
// ============================================================================
__global__ __launch_bounds__(512, 4) void k1_gemm_wcomb(
    const float* __restrict__ pun, const float* __restrict__ Bw,
    const float* __restrict__ bias, float* __restrict__ C,
    const float* __restrict__ wlin, const float* __restrict__ wout,
    const float* __restrict__ bout, const float* __restrict__ blin,
    float* __restrict__ wcomb, float* __restrict__ wsbias)
{
  __shared__ float lds[14336];
  const int t = threadIdx.x;
  const int w = t >> 6, l = t & 63;
  const int tx = l & 7, ty = l >> 3;     // frag: n=tx*4, m=ty*2
  const int gm = l & 15, gq = l >> 4;    // A-staging: row, k-quad
  const int bl = l & 31, bh = l >> 5;    // B-staging: row, k-half
  const int kbase = w * 96;
  const int AW = w * 1792, BW = AW + 640;

  float4 aF, bF0, bF1;
  float acc[2][4] = {};

#define STAGE_A(b) {                                                         \
    int Ab = AW + (b) * 320;                                                 \
    lds[Ab + (gq*4+0)*20 + gm] = aF.x;                                       \
    lds[Ab + (gq*4+1)*20 + gm] = aF.y;                                       \
    lds[Ab + (gq*4+2)*20 + gm] = aF.z;                                       \
    lds[Ab + (gq*4+3)*20 + gm] = aF.w; }

#define INNER(b) {                                                           \
    int Ab = AW + (b) * 320, Bb = BW + (b) * 576;                            \
    _Pragma("unroll")                                                        \
    for (int kk = 0; kk < 16; kk++) {                                        \
      float2 a  = *(float2*)&lds[Ab + kk * 20 + ty * 2];                     \
      float4 bb = *(float4*)&lds[Bb + kk * 36 + tx * 4];                     \
      acc[0][0] += a.x*bb.x; acc[0][1] += a.x*bb.y;                          \
      acc[0][2] += a.x*bb.z; acc[0][3] += a.x*bb.w;                          \
      acc[1][0] += a.y*bb.x; acc[1][1] += a.y*bb.y;                          \
      acc[1][2] += a.y*bb.z; acc[1][3] += a.y*bb.w;                          \
    } }

  if (blockIdx.x < 576) {
    // ------------------------------ GEMM1 ---------------------------------
    const int c  = blockIdx.x;
    const int bm = (c / 72) * 16, bn = (c % 72) * 32;
    const float* arow = pun + (size_t)(bm + gm) * EMB;
    const float* brow = Bw + (size_t)(bn + bl) * EMB;

#define G_LOAD(s) {                                                          \
    int k0 = kbase + (s) * 16;                                               \
    aF  = *(const float4*)&arow[k0 + gq * 4];                                \
    bF0 = *(const float4*)&brow[k0 + bh * 8 + 0];                            \
    bF1 = *(const float4*)&brow[k0 + bh * 8 + 4]; }

#define G_WRITE(b) {                                                         \
    STAGE_A(b)                                                               \
    int Bb = BW + (b) * 576;                                                 \
    lds[Bb + (bh*8+0)*36 + bl] = bF0.x; lds[Bb + (bh*8+1)*36 + bl] = bF0.y;  \
    lds[Bb + (bh*8+2)*36 + bl] = bF0.z; lds[Bb + (bh*8+3)*36 + bl] = bF0.w;  \
    lds[Bb + (bh*8+4)*36 + bl] = bF1.x; lds[Bb + (bh*8+5)*36 + bl] = bF1.y;  \
    lds[Bb + (bh*8+6)*36 + bl] = bF1.z; lds[Bb + (bh*8+7)*36 + bl] = bF1.w; }

    G_LOAD(0); G_WRITE(0);
    for (int s = 0; s < 6; s++) {
      int b = s & 1;
      if (s < 5) G_LOAD(s + 1);
      INNER(b);
      if (s < 5) G_WRITE(b ^ 1);
    }
#undef G_LOAD
#undef G_WRITE
#pragma unroll
    for (int i = 0; i < 2; i++)
      *(float4*)&lds[AW + (ty*2 + i) * 32 + tx * 4] =
          make_float4(acc[i][0], acc[i][1], acc[i][2], acc[i][3]);
    __syncthreads();
    int m = t >> 5, n = t & 31;
    float v = lds[0*1792 + t] + lds[1*1792 + t] + lds[2*1792 + t] + lds[3*1792 + t]
            + lds[4*1792 + t] + lds[5*1792 + t] + lds[6*1792 + t] + lds[7*1792 + t]
            + bias[bn + n];
    C[(size_t)(bm + m) * K3E + bn + n] = v;
  } else if (blockIdx.x < 744) {
    // ------------------------------ W_comb --------------------------------
    const int cc = blockIdx.x - 576;
    const int bm = (cc / 24) * 16, bn = (cc % 24) * 32;
    const int wi = l >> 2;                 // k-row 0..15
    const int j4 = (l & 3) * 8;            // e-offset 0,8,16,24
    int arow_i = bm + gm; if (arow_i > 99) arow_i = 99;
    const float* arow = wlin + (size_t)arow_i * EMB;

#define W_LOAD(s) {                                                          \
    int k0 = kbase + (s) * 16;                                               \
    aF  = *(const float4*)&arow[k0 + gq * 4];                                \
    const float* wr = wout + (size_t)(k0 + wi) * EMB + bn + j4;              \
    bF0 = *(const float4*)&wr[0];                                            \
    bF1 = *(const float4*)&wr[4]; }

#define W_WRITE(b) {                                                         \
    STAGE_A(b)                                                               \
    int Bb = BW + (b) * 576;                                                 \
    *(float4*)&lds[Bb + wi*36 + j4]     = bF0;                               \
    *(float4*)&lds[Bb + wi*36 + j4 + 4] = bF1; }

    W_LOAD(0); W_WRITE(0);
    for (int s = 0; s < 6; s++) {
      int b = s & 1;
      if (s < 5) W_LOAD(s + 1);
      INNER(b);
      if (s < 5) W_WRITE(b ^ 1);
    }
#undef W_LOAD
#undef W_WRITE
#pragma unroll
    for (int i = 0; i < 2; i++)
      *(float4*)&lds[AW + (ty*2 + i) * 32 + tx * 4] =
          make_float4(acc[i][0], acc[i][1], acc[i][2], acc[i][3]);
    __syncthreads();
    int m = t >> 5, n = t & 31;
    if (bm + m < 100) {
      float v = lds[0*1792 + t] + lds[1*1792 + t] + lds[2*1792 + t] + lds[3*1792 + t]
              + lds[4*1792 + t] + lds[5*1792 + t] + lds[6*1792 + t] + lds[7*1792 + t];
      wcomb[(size_t)(bm + m) * EMB + bn + n] = v;
    }
  } else {
    // --------------------------- bias_comb --------------------------------
    if (t < 400) {
      int col = t >> 2, q = t & 3;
      const float* wr = wlin + (size_t)col * EMB + q * 192;
      const float* br = bout + q * 192;
      float p = 0.f;
#pragma unroll
      for (int j = 0; j < 48; j++) {
        float4 wv = *(const float4*)&wr[j * 4];
        float4 bv = *(const float4*)&br[j * 4];
        p += wv.x*bv.x + wv.y*bv.y + wv.z*bv.z + wv.w*bv.w;
      }
      p += __shfl_xor(p, 1); p += __shfl_xor(p, 2);
      if (q == 0) wsbias[col] = p + blin[col];
    }
  }
#undef STAGE_A
#undef INNER
}

// ============================================================================
// K2: attention (token 0 only) + fused final GEMM via per-head atomicAdd.
// 128 blocks: h = bx>>3, 16-row l-tile. 256 thr.
// After the (verified) attn body, the 16x48 ctx tile goes to LDS and each
// block applies its head's 48-wide wcomb slice: out[l, c] += ctx_h . wcomb.
// h==0 blocks also add wsbias. out was zeroed by K0.
// ============================================================================
__global__ __launch_bounds__(256) void k2_attn_fused(
    const float* __restrict__ proj, const float* __restrict__ wcomb,
    const float* __restrict__ wsbias, float* __restrict__ out)
{
  __shared__ float lds[14080];   // ks 6656 | vs 6656 | sctx 768
  float* ks   = lds;
  float* vs   = lds + 6656;
  float* sctx = lds + 13312;
  int h  = blockIdx.x >> 3;
  int l0 = (blockIdx.x & 7) * 16;
  int t  = threadIdx.x;

  for (int i = t; i < 128 * 12; i += 256) {
    int m  = i / 12;
    int dd = (i - m * 12) * 4;
    float4 kv = *(const float4*)&proj[(size_t)m * K3E + EMB     + h * DHD + dd];
    float4 vv = *(const float4*)&proj[(size_t)m * K3E + 2 * EMB + h * DHD + dd];
    *(float4*)&ks[m * 52 + dd] = kv;
    *(float4*)&vs[m * 52 + dd] = vv;
  }

  int l  = t >> 4;
  int g  = t & 15;
  int lg = l0 + l;
  const float scale = 0.14433756729740643f;  // 48^-0.5
  float q[48];
#pragma unroll
  for (int jj = 0; jj < 12; jj++) {
    float4 qv = *(const float4*)&proj[(size_t)lg * K3E + h * DHD + jj * 4];
    q[jj*4+0] = qv.x * scale; q[jj*4+1] = qv.y * scale;
    q[jj*4+2] = qv.z * scale; q[jj*4+3] = qv.w * scale;
  }
  __syncthreads();

  float sv[8];
  float smax = -1e30f;
#pragma unroll
  for (int jm = 0; jm < 8; jm++) {
    int m = g + jm * 16;
    float s = 0.0f;
#pragma unroll
    for (int dq = 0; dq < 12; dq++) {
      float4 kv = *(const float4*)&ks[m * 52 + dq * 4];
      s += q[dq*4+0]*kv.x + q[dq*4+1]*kv.y + q[dq*4+2]*kv.z + q[dq*4+3]*kv.w;
    }
    sv[jm] = s;
    smax = fmaxf(smax, s);
  }
#pragma unroll
  for (int off = 1; off < 16; off <<= 1) smax = fmaxf(smax, __shfl_xor(smax, off));
  float ssum = 0.0f;
#pragma unroll
  for (int jm = 0; jm < 8; jm++) { float e = __expf(sv[jm] - smax); sv[jm] = e; ssum += e; }
#pragma unroll
  for (int off = 1; off < 16; off <<= 1) ssum += __shfl_xor(ssum, off);
  float inv = 1.0f / ssum;
#pragma unroll
  for (int jm = 0; jm < 8; jm++) sv[jm] *= inv;

  float acc[48] = {};
#pragma unroll
  for (int jm = 0; jm < 8; jm++) {
    int m = g + jm * 16;
    float p = sv[jm];
#pragma unroll
    for (int dq = 0; dq < 12; dq++) {
      float4 vv = *(const float4*)&vs[m * 52 + dq * 4];
      acc[dq*4+0] += p*vv.x; acc[dq*4+1] += p*vv.y;
      acc[dq*4+2] += p*vv.z; acc[dq*4+3] += p*vv.w;
    }
  }

  {
    float buf[24];
    if (g & 8) {
#pragma unroll
      for (int d = 0; d < 24; d++) buf[d] = acc[d];
    } else {
#pragma unroll
      for (int d = 0; d < 24; d++) buf[d] = acc[d + 24];
    }
#pragma unroll
    for (int d = 0; d < 24; d++) buf[d] = __shfl_xor(buf[d], 8);
    if (g & 8) {
#pragma unroll
      for (int d = 0; d < 24; d++) acc[d] = acc[d + 24] + buf[d];
    } else {
#pragma unroll
      for (int d = 0; d < 24; d++) acc[d] = acc[d] + buf[d];
    }
  }
  {
    float buf[12];
    if (g & 4) {
#pragma unroll
      for (int d = 0; d < 12; d++) buf[d] = acc[d];
    } else {
#pragma unroll
      for (int d = 0; d < 12; d++) buf[d] = acc[d + 12];
    }
#pragma unroll
    for (int d = 0; d < 12; d++) buf[d] = __shfl_xor(buf[d], 4);
    if (g & 4) {
#pragma unroll
      for (int d = 0; d < 12; d++) acc[d] = acc[d + 12] + buf[d];
    } else {
#pragma unroll
      for (int d = 0; d < 12; d++) acc[d] = acc[d] + buf[d];
    }
  }
  {
    float buf[6];
    if (g & 2) {
#pragma unroll
      for (int d = 0; d < 6; d++) buf[d] = acc[d];
    } else {
#pragma unroll
      for (int d = 0; d < 6; d++) buf[d] = acc[d + 6];
    }
#pragma unroll
    for (int d = 0; d < 6; d++) buf[d] = __shfl_xor(buf[d], 2);
    if (g & 2) {
#pragma unroll
      for (int d = 0; d < 6; d++) acc[d] = acc[d + 6] + buf[d];
    } else {
#pragma unroll
      for (int d = 0; d < 6; d++) acc[d] = acc[d] + buf[d];
    }
  }
  {
    float buf[3];
    if (g & 1) {
#pragma unroll
      for (int d = 0; d < 3; d++) buf[d] = acc[d];
    } else {
#pragma unroll
      for (int d = 0; d < 3; d++) buf[d] = acc[d + 3];
    }
#pragma unroll
    for (int d = 0; d < 3; d++) buf[d] = __shfl_xor(buf[d], 1);
    if (g & 1) {
#pragma unroll
      for (int d = 0; d < 3; d++) acc[d] = acc[d + 3] + buf[d];
    } else {
#pragma unroll
      for (int d = 0; d < 3; d++) acc[d] = acc[d] + buf[d];
    }
  }
  // ctx tile -> LDS (row l, cols g*3..g*3+2)
#pragma unroll
  for (int j = 0; j < 3; j++) sctx[l * 48 + g * 3 + j] = acc[j];
  __syncthreads();

  // ---- fused final GEMM slice: out[l0+r, c] += sctx[r,:] . wcomb[c, h*48:]
  {
    int r  = t >> 4;         // 0..15 row in tile
    int cg = t & 15;         // col group: cols cg*7 .. cg*7+6 (<100)
    float cr[48];
#pragma unroll
    for (int e = 0; e < 48; e++) cr[e] = sctx[r * 48 + e];
#pragma unroll
    for (int j = 0; j < 7; j++) {
      int col = cg * 7 + j;
      if (col < 100) {
        const float* wr = wcomb + (size_t)col * EMB + h * DHD;
        float s = 0.f;
#pragma unroll
        for (int e4 = 0; e4 < 12; e4++) {
          float4 wv = *(const float4*)&wr[e4 * 4];
          s += cr[e4*4+0]*wv.x + cr[e4*4+1]*wv.y + cr[e4*4+2]*wv.z + cr[e4*4+3]*wv.w;
        }
        if (h == 0) s += wsbias[col];
        atomicAdd(&out[(size_t)(l0 + r) * 100 + col], s);
      }
    }
  }
}

// ---------------------------------------------------------------------------
extern "C" void kernel_launch(void* const* d_in, const int* in_sizes, int n_in,
                              void* d_out, int out_size, void* d_ws, size_t ws_size,
                              hipStream_t stream) {
  const float* lhs   = (const float*)d_in[0];
  // d_in[1] sense_emb: dead — only attn_out[:,0,:] is used downstream.
  const int*   loc   = (const int*)  d_in[2];
  const float* w_in  = (const float*)d_in[3];
  const float* b_in  = (const float*)d_in[4];
  const float* w_out = (const float*)d_in[5];
  const float* b_out = (const float*)d_in[6];
  const float* w_lin = (const float*)d_in[7];
  const float* b_lin = (const float*)d_in[8];
  float* out = (float*)d_out;

  char* ws = (char*)d_ws;
  float* pun    = (float*)(ws);                     // 128*768  = 393216 B
  float* proj   = (float*)(ws + 393216);            // 128*2304 = 1179648 B
  float* wcomb  = (float*)(ws + 1572864);           // 100*768  = 307200 B
  float* wsbias = (float*)(ws + 1880064);           // 100 floats

  k0_pun<<<96, 256, 0, stream>>>(lhs, loc, pun, out);
  k1_gemm_wcomb<<<745, 512, 0, stream>>>(pun, w_in, b_in, proj,
                                         w_lin, w_out, b_out, b_lin,
                                         wcomb, wsbias);
  k2_attn_fused<<<128, 256, 0, stream>>>(proj, wcomb, wsbias, out);
}